// Round 18
// baseline (229.959 us; speedup 1.0000x reference)
//
#include <hip/hip_runtime.h>
#include <math.h>

#define N_NODES 200000
#define E_EDGES 100000
#define TIME_DIM 100
#define RAW_DIM 484   // 128 + 128 + 128 + 100
#define CAP 12        // per-node direct slots
#define OVF_MAX 8192

typedef short  bf16x8 __attribute__((ext_vector_type(8)));
typedef float  f32x4  __attribute__((ext_vector_type(4)));
typedef unsigned int uint;

__device__ __forceinline__ short f2bf(float f) {
    unsigned u = __builtin_bit_cast(unsigned, f);
    u = (u + 0x7FFFu + ((u >> 16) & 1u)) >> 16;   // RNE
    return (short)u;
}
__device__ __forceinline__ float bf2f(unsigned short u) {
    return __builtin_bit_cast(float, ((unsigned)u) << 16);
}
__device__ __forceinline__ float fsigmoid(float x) {
    return __builtin_amdgcn_rcpf(1.0f + __expf(-x));
}
__device__ __forceinline__ float ftanh(float x) {
    float t = __expf(2.0f * x);
    return 1.0f - 2.0f * __builtin_amdgcn_rcpf(t + 1.0f);
}
__device__ __forceinline__ unsigned cvtpk(float a, float b) {
    unsigned r;
    asm("v_cvt_pk_bf16_f32 %0, %1, %2" : "=v"(r) : "v"(a), "v"(b));
    return r;
}
__device__ __forceinline__ bf16x8 pack8(float4 a, float4 b) {
    uint4 u = {cvtpk(a.x, a.y), cvtpk(a.z, a.w), cvtpk(b.x, b.y), cvtpk(b.z, b.w)};
    return __builtin_bit_cast(bf16x8, u);
}

// ---------------------------------------------------------------------------
// Setup: weight-fragment packs + ticket slot lists (STANDALONE — proven).
// ---------------------------------------------------------------------------
__global__ __launch_bounds__(256) void tgn_setup(
    const float* __restrict__ Wih, const float* __restrict__ Whh,
    short* __restrict__ wfg,
    const float* __restrict__ msgW, short* __restrict__ wfm,
    const int* __restrict__ src, const int* __restrict__ dst,
    uint* __restrict__ idxv, uint* __restrict__ cnt, uint* __restrict__ ovf)
{
    int b = blockIdx.x;
    int tid = threadIdx.x;
    if (b < 512) {
        int idx = b * 256 + tid;                 // 0 .. 131071
        int j = idx & 7;
        int l = (idx >> 3) & 63;
        int s = (idx >> 9) & 7;
        int t = idx >> 12;
        int n = t * 16 + (l & 15);
        int k = s * 32 + (l >> 4) * 8 + j;
        int half = k >> 7;
        int kk = k & 127;
        float v;
        if (n < 256) {
            v = half ? Whh[(size_t)n * 128 + kk] : Wih[(size_t)n * 128 + kk];
        } else if (n < 384) {
            v = half ? 0.0f : Wih[(size_t)n * 128 + kk];
        } else {
            v = half ? Whh[(size_t)(n - 128) * 128 + kk] : 0.0f;
        }
        wfg[idx] = f2bf(v);
    } else if (b < 768) {
        int idx = (b - 512) * 256 + tid;         // 0 .. 65535
        int j = idx & 7;
        int l = (idx >> 3) & 63;
        int s = (idx >> 9) & 15;
        int t = idx >> 13;
        int n = t * 16 + (l & 15);
        int k = s * 32 + (l >> 4) * 8 + j;
        float v = (k < RAW_DIM) ? msgW[(size_t)n * RAW_DIM + k] : 0.0f;
        wfm[idx] = f2bf(v);
    } else {
        int i = (b - 768) * 256 + tid;
        if (i < E_EDGES) {
            int s = src[i];
            int d = dst[i];
            uint rs = atomicAdd(&cnt[s], 1u);
            if (rs < (uint)CAP) {
                idxv[(size_t)s * CAP + rs] = (uint)i;
            } else {
                uint o = atomicAdd(&ovf[0], 1u);
                if (o < OVF_MAX) { ovf[1 + 2 * o] = (uint)s; ovf[2 + 2 * o] = (uint)i; }
            }
            uint rd = atomicAdd(&cnt[d], 1u);
            if (rd < (uint)CAP) {
                idxv[(size_t)d * CAP + rd] = (uint)i;
            } else {
                uint o = atomicAdd(&ovf[0], 1u);
                if (o < OVF_MAX) { ovf[1 + 2 * o] = (uint)d; ovf[2 + 2 * o] = (uint)i; }
            }
        }
    }
}

// ---------------------------------------------------------------------------
// Kernel A (bf16 store): register-gather MFMA message MLP, NO atomics.
// launch_bounds(128,2) — PROVEN. (128,4) breaks correctness (r17 ledger):
// the 112-live-reg epilogue has no headroom; do not squeeze this kernel.
// ---------------------------------------------------------------------------
#define MTE 32

__global__ __launch_bounds__(128, 2) void tgn_msg_bf(
    const float* __restrict__ memory,
    const float* __restrict__ last_update,
    const float* __restrict__ timestamps,
    const float* __restrict__ edge_features,
    const float* __restrict__ msg_b,
    const float* __restrict__ time_w,
    const float* __restrict__ time_b,
    const int*   __restrict__ src,
    const int*   __restrict__ dst,
    const short* __restrict__ wfm,
    short* __restrict__ msgb)
{
    const int tid  = threadIdx.x;
    const int wv   = tid >> 6;
    const int l    = tid & 63;
    const int lrow = l & 15;
    const int lkg  = l >> 4;
    const int e0   = blockIdx.x * MTE + wv * 16;
    const int e    = e0 + lrow;

    const int sid = src[e];
    const int did = dst[e];
    const float dt = timestamps[e] - last_update[sid];

    const float* srcm = memory        + (size_t)sid * 128 + lkg * 8;
    const float* dstm = memory        + (size_t)did * 128 + lkg * 8;
    const float* ef   = edge_features + (size_t)e   * 128 + lkg * 8;
    float4 bufS[8], bufD[8], bufE[8];
#pragma unroll
    for (int s = 0; s < 4; ++s) {
        bufS[2 * s]     = *reinterpret_cast<const float4*>(srcm + s * 32);
        bufS[2 * s + 1] = *reinterpret_cast<const float4*>(srcm + s * 32 + 4);
        bufD[2 * s]     = *reinterpret_cast<const float4*>(dstm + s * 32);
        bufD[2 * s + 1] = *reinterpret_cast<const float4*>(dstm + s * 32 + 4);
        bufE[2 * s]     = *reinterpret_cast<const float4*>(ef + s * 32);
        bufE[2 * s + 1] = *reinterpret_cast<const float4*>(ef + s * 32 + 4);
    }

    bf16x8 afr[16];
#pragma unroll
    for (int s = 12; s < 16; ++s) {
        int k0 = s * 32 + lkg * 8;
        float4 lo, hi;
#pragma unroll
        for (int j = 0; j < 8; ++j) {
            int k = k0 + j;
            float v = 0.0f;
            if (k < RAW_DIM) {
                int t = k - 384;
                v = __cosf(fmaf(dt, time_w[t], time_b[t]));
            }
            if (j < 4) (&lo.x)[j] = v; else (&hi.x)[j - 4] = v;
        }
        afr[s] = pack8(lo, hi);
    }

#pragma unroll
    for (int s = 0; s < 4; ++s) {
        afr[s]     = pack8(bufS[2 * s], bufS[2 * s + 1]);
        afr[4 + s] = pack8(bufD[2 * s], bufD[2 * s + 1]);
        afr[8 + s] = pack8(bufE[2 * s], bufE[2 * s + 1]);
    }

    f32x4 acc[8];
#pragma unroll
    for (int t = 0; t < 8; ++t) acc[t] = (f32x4){0.f, 0.f, 0.f, 0.f};

#pragma unroll
    for (int s = 0; s < 16; ++s) {
#pragma unroll
        for (int t = 0; t < 8; ++t) {
            bf16x8 B = *reinterpret_cast<const bf16x8*>(
                &wfm[(size_t)(((t * 16 + s) * 64) + l) * 8]);
            acc[t] = __builtin_amdgcn_mfma_f32_16x16x32_bf16(afr[s], B, acc[t], 0, 0, 0);
        }
    }

    const bool even = (l & 1) == 0;
#pragma unroll
    for (int r = 0; r < 4; ++r) {
        int erow = e0 + lkg * 4 + r;
#pragma unroll
        for (int t = 0; t < 8; ++t) {
            int j = t * 16 + lrow;
            float m = acc[t][r] + msg_b[j];
            float mo = __shfl_xor(m, 1);
            if (even) {
                unsigned pk = cvtpk(m, mo);
                *reinterpret_cast<unsigned*>(&msgb[(size_t)erow * 128 + j]) = pk;
            }
        }
    }
}

// ---------------------------------------------------------------------------
// Kernel B: 64-node / 512-thread / 8-wave GRU (round-16 proven).
// ---------------------------------------------------------------------------
#define GNT 64

__global__ __launch_bounds__(512, 4) void tgn_gru_bf64(
    const float* __restrict__ memory,
    const float* __restrict__ last_update,
    const float* __restrict__ timestamps,
    const float* __restrict__ b_ih,
    const float* __restrict__ b_hh,
    const short* __restrict__ wfrag,
    const short* __restrict__ msgb,
    const uint*  __restrict__ idxv,
    const uint*  __restrict__ cnt,
    const uint*  __restrict__ ovf,
    float* __restrict__ out)
{
    __shared__ short X[GNT][264];
    __shared__ float cntS[GNT];

    const int tid = threadIdx.x;
    const int n0 = blockIdx.x * GNT;

    const int nloc = tid >> 3;     // 0..63
    const int p    = tid & 7;      // dims [p*16, p*16+16)
    const int node = n0 + nloc;

    const uint c = cnt[node];
    if (p == 0) cntS[nloc] = (float)c;

#pragma unroll
    for (int it = 0; it < 4; ++it) {
        int i = tid + it * 512;
        int m = i >> 5;
        int c4 = (i & 31) * 4;
        float4 mv = *reinterpret_cast<const float4*>(&memory[(size_t)(n0 + m) * 128 + c4]);
        uint2 u = {cvtpk(mv.x, mv.y), cvtpk(mv.z, mv.w)};
        *reinterpret_cast<uint2*>(&X[m][128 + c4]) = u;
    }

    // gather-aggregate agg -> X[:, 0:128]; 8 threads/node, 16 dims each
    {
        float a[16];
#pragma unroll
        for (int q = 0; q < 16; ++q) a[q] = 0.0f;
        const uint cm = (c < (uint)CAP) ? c : (uint)CAP;
        if (cm > 0u) {
            const uint* ip = idxv + (size_t)node * CAP;
            uint4 i0 = *reinterpret_cast<const uint4*>(ip);
            uint4 i1 = {0, 0, 0, 0}, i2 = {0, 0, 0, 0};
            if (cm > 4u) i1 = *reinterpret_cast<const uint4*>(ip + 4);
            if (cm > 8u) i2 = *reinterpret_cast<const uint4*>(ip + 8);
            uint idxs[12];
            idxs[0] = i0.x; idxs[1] = i0.y; idxs[2]  = i0.z; idxs[3]  = i0.w;
            idxs[4] = i1.x; idxs[5] = i1.y; idxs[6]  = i1.z; idxs[7]  = i1.w;
            idxs[8] = i2.x; idxs[9] = i2.y; idxs[10] = i2.z; idxs[11] = i2.w;
#pragma unroll
            for (int i = 0; i < 12; ++i) {
                if ((uint)i < cm) {
                    const short* row = msgb + (size_t)idxs[i] * 128 + p * 16;
                    bf16x8 v0 = *reinterpret_cast<const bf16x8*>(row);
                    bf16x8 v1 = *reinterpret_cast<const bf16x8*>(row + 8);
#pragma unroll
                    for (int q = 0; q < 8; ++q) {
                        a[q]     += bf2f((unsigned short)v0[q]);
                        a[8 + q] += bf2f((unsigned short)v1[q]);
                    }
                }
            }
        }
        if (c > (uint)CAP) {                   // rare: scan overflow list
            uint L = ovf[0];
            if (L > OVF_MAX) L = OVF_MAX;
            for (uint i = 0; i < L; ++i) {
                if (ovf[1 + 2 * i] == (uint)node) {
                    uint eid = ovf[2 + 2 * i];
                    const short* row = msgb + (size_t)eid * 128 + p * 16;
                    bf16x8 v0 = *reinterpret_cast<const bf16x8*>(row);
                    bf16x8 v1 = *reinterpret_cast<const bf16x8*>(row + 8);
#pragma unroll
                    for (int q = 0; q < 8; ++q) {
                        a[q]     += bf2f((unsigned short)v0[q]);
                        a[8 + q] += bf2f((unsigned short)v1[q]);
                    }
                }
            }
        }
        float inv = (c > 0u) ? (1.0f / (float)c) : 0.0f;
#pragma unroll
        for (int q = 0; q < 16; ++q) a[q] *= inv;
        float4 A0 = {a[0], a[1], a[2], a[3]};
        float4 A1 = {a[4], a[5], a[6], a[7]};
        float4 A2 = {a[8], a[9], a[10], a[11]};
        float4 A3 = {a[12], a[13], a[14], a[15]};
        *reinterpret_cast<bf16x8*>(&X[nloc][p * 16])     = pack8(A0, A1);
        *reinterpret_cast<bf16x8*>(&X[nloc][p * 16 + 8]) = pack8(A2, A3);
    }
    __syncthreads();

    const int w    = tid >> 6;     // wave 0..7 -> j-slice [w*16, w*16+16)
    const int l    = tid & 63;
    const int lrow = l & 15;
    const int lkg  = l >> 4;

    f32x4 acc[4][4];   // [quadrant][mt]
#pragma unroll
    for (int q = 0; q < 4; q++)
#pragma unroll
        for (int mt = 0; mt < 4; mt++)
            acc[q][mt] = (f32x4){0.f, 0.f, 0.f, 0.f};

    for (int s = 0; s < 8; ++s) {
        bf16x8 A[4];
#pragma unroll
        for (int mt = 0; mt < 4; ++mt)
            A[mt] = *reinterpret_cast<const bf16x8*>(&X[mt * 16 + lrow][s * 32 + lkg * 8]);
#pragma unroll
        for (int q = 0; q < 4; ++q) {
            int t = q * 8 + w;
            bf16x8 B = *reinterpret_cast<const bf16x8*>(&wfrag[(size_t)(((t * 8 + s) * 64) + l) * 8]);
#pragma unroll
            for (int mt = 0; mt < 4; ++mt)
                acc[q][mt] = __builtin_amdgcn_mfma_f32_16x16x32_bf16(
                    A[mt], B, acc[q][mt], 0, 0, 0);
        }
    }

    const float ts0 = timestamps[0];

    {
        int j = w * 16 + lrow;
        float br  = b_ih[j]       + b_hh[j];
        float bz  = b_ih[128 + j] + b_hh[128 + j];
        float bin = b_ih[256 + j];
        float bhn = b_hh[256 + j];
#pragma unroll
        for (int mt = 0; mt < 4; ++mt) {
#pragma unroll
            for (int r = 0; r < 4; ++r) {
                int mloc = mt * 16 + lkg * 4 + r;
                int nodew = n0 + mloc;
                float rg  = acc[0][mt][r] + br;
                float zg  = acc[1][mt][r] + bz;
                float ing = acc[2][mt][r] + bin;
                float hng = acc[3][mt][r] + bhn;
                float rr = fsigmoid(rg);
                float zz = fsigmoid(zg);
                float nn = ftanh(ing + rr * hng);
                float mv = bf2f((unsigned short)X[mloc][128 + j]);
                float h  = (1.0f - zz) * nn + zz * mv;
                out[(size_t)nodew * 128 + j] = (cntS[mloc] > 0.0f) ? h : mv;
            }
        }
    }

    if (tid < GNT) {
        int noded = n0 + tid;
        out[(size_t)N_NODES * 128 + noded] = (cntS[tid] > 0.0f) ? ts0 : last_update[noded];
    }
}

// ---------------------------------------------------------------------------
// Fallback (round-7 proven): f32 atomics via d_out.
// ---------------------------------------------------------------------------
#define TE 32
#define GNTF 32

__global__ __launch_bounds__(256, 2) void tgn_msg_mfma(
    const float* __restrict__ memory,
    const float* __restrict__ last_update,
    const float* __restrict__ timestamps,
    const float* __restrict__ edge_features,
    const float* __restrict__ msg_b,
    const float* __restrict__ time_w,
    const float* __restrict__ time_b,
    const int*   __restrict__ src,
    const int*   __restrict__ dst,
    const short* __restrict__ wfm,
    float* __restrict__ sums,
    float* __restrict__ counts)
{
    __shared__ short X[TE][520];
    __shared__ int   sid[TE];
    __shared__ int   did[TE];
    __shared__ float dtS[TE];

    const int tid = threadIdx.x;
    const int e0  = blockIdx.x * TE;

    if (tid < TE) {
        int s = src[e0 + tid];
        int d = dst[e0 + tid];
        sid[tid] = s;
        did[tid] = d;
        dtS[tid] = timestamps[e0 + tid] - last_update[s];
        atomicAdd(&counts[s], 1.0f);
        atomicAdd(&counts[d], 1.0f);
    }
    __syncthreads();

    for (int i = tid; i < TE * 128; i += 256) {
        int e = i >> 7;
        int c = (i & 127) * 4;
        float4 v;
        if (c < 128) {
            v = *reinterpret_cast<const float4*>(&memory[(size_t)sid[e] * 128 + c]);
        } else if (c < 256) {
            v = *reinterpret_cast<const float4*>(&memory[(size_t)did[e] * 128 + (c - 128)]);
        } else if (c < 384) {
            v = *reinterpret_cast<const float4*>(&edge_features[(size_t)(e0 + e) * 128 + (c - 256)]);
        } else if (c < 484) {
            float dt = dtS[e];
            int t = c - 384;
            v.x = __cosf(fmaf(dt, time_w[t + 0], time_b[t + 0]));
            v.y = __cosf(fmaf(dt, time_w[t + 1], time_b[t + 1]));
            v.z = __cosf(fmaf(dt, time_w[t + 2], time_b[t + 2]));
            v.w = __cosf(fmaf(dt, time_w[t + 3], time_b[t + 3]));
        } else {
            v.x = v.y = v.z = v.w = 0.0f;
        }
        short4 s4;
        s4.x = f2bf(v.x); s4.y = f2bf(v.y); s4.z = f2bf(v.z); s4.w = f2bf(v.w);
        *reinterpret_cast<short4*>(&X[e][c]) = s4;
    }
    __syncthreads();

    const int w    = tid >> 6;
    const int l    = tid & 63;
    const int lrow = l & 15;
    const int lkg  = l >> 4;
    const int et   = w & 1;
    const int nh   = w >> 1;

    f32x4 acc[4];
#pragma unroll
    for (int n = 0; n < 4; n++) acc[n] = (f32x4){0.f, 0.f, 0.f, 0.f};

#pragma unroll 4
    for (int s = 0; s < 16; ++s) {
        bf16x8 A = *reinterpret_cast<const bf16x8*>(&X[et * 16 + lrow][s * 32 + lkg * 8]);
#pragma unroll
        for (int ntl = 0; ntl < 4; ++ntl) {
            int t = nh * 4 + ntl;
            bf16x8 B = *reinterpret_cast<const bf16x8*>(&wfm[(size_t)(((t * 16 + s) * 64) + l) * 8]);
            acc[ntl] = __builtin_amdgcn_mfma_f32_16x16x32_bf16(A, B, acc[ntl], 0, 0, 0);
        }
    }

#pragma unroll
    for (int ntl = 0; ntl < 4; ++ntl) {
        int j = nh * 64 + ntl * 16 + lrow;
        float bias = msg_b[j];
#pragma unroll
        for (int r = 0; r < 4; ++r) {
            int el = et * 16 + lkg * 4 + r;
            float m = acc[ntl][r] + bias;
            atomicAdd(&sums[(size_t)sid[el] * 128 + j], m);
            atomicAdd(&sums[(size_t)did[el] * 128 + j], m);
        }
    }
}

__global__ __launch_bounds__(256, 3) void tgn_gru_mfma(
    const float* __restrict__ memory,
    const float* __restrict__ last_update,
    const float* __restrict__ timestamps,
    const float* __restrict__ b_ih,
    const float* __restrict__ b_hh,
    const short* __restrict__ wfrag,
    float* __restrict__ out)
{
    __shared__ short X[GNTF][264];
    __shared__ float cntS[GNTF];

    const int tid = threadIdx.x;
    const int n0 = blockIdx.x * GNTF;
    const float* sums   = out;
    const float* counts = out + (size_t)N_NODES * 128;

    if (tid < GNTF) cntS[tid] = counts[n0 + tid];
    __syncthreads();

    for (int i = tid; i < GNTF * 32; i += 256) {
        int m = i >> 5;
        int c = (i & 31) * 4;
        float inv = 1.0f / fmaxf(cntS[m], 1.0f);
        float4 v = *reinterpret_cast<const float4*>(&sums[(size_t)(n0 + m) * 128 + c]);
        short4 a4;
        a4.x = f2bf(v.x * inv); a4.y = f2bf(v.y * inv);
        a4.z = f2bf(v.z * inv); a4.w = f2bf(v.w * inv);
        *reinterpret_cast<short4*>(&X[m][c]) = a4;
        float4 mv = *reinterpret_cast<const float4*>(&memory[(size_t)(n0 + m) * 128 + c]);
        short4 m4;
        m4.x = f2bf(mv.x); m4.y = f2bf(mv.y); m4.z = f2bf(mv.z); m4.w = f2bf(mv.w);
        *reinterpret_cast<short4*>(&X[m][128 + c]) = m4;
    }
    __syncthreads();

    const int w    = tid >> 6;
    const int l    = tid & 63;
    const int lrow = l & 15;
    const int lkg  = l >> 4;

    f32x4 acc[4][2][2];
#pragma unroll
    for (int q = 0; q < 4; q++)
#pragma unroll
        for (int jt = 0; jt < 2; jt++)
#pragma unroll
            for (int mt = 0; mt < 2; mt++)
                acc[q][jt][mt] = (f32x4){0.f, 0.f, 0.f, 0.f};

    for (int s = 0; s < 8; ++s) {
        bf16x8 A[2];
#pragma unroll
        for (int mt = 0; mt < 2; ++mt)
            A[mt] = *reinterpret_cast<const bf16x8*>(&X[mt * 16 + lrow][s * 32 + lkg * 8]);
#pragma unroll
        for (int q = 0; q < 4; ++q)
#pragma unroll
            for (int jt = 0; jt < 2; ++jt) {
                int t = q * 8 + w * 2 + jt;
                bf16x8 B = *reinterpret_cast<const bf16x8*>(&wfrag[(size_t)(((t * 8 + s) * 64) + l) * 8]);
#pragma unroll
                for (int mt = 0; mt < 2; ++mt)
                    acc[q][jt][mt] = __builtin_amdgcn_mfma_f32_16x16x32_bf16(
                        A[mt], B, acc[q][jt][mt], 0, 0, 0);
            }
    }

    const float ts0 = timestamps[0];
#pragma unroll
    for (int jt = 0; jt < 2; ++jt) {
        int j = w * 32 + jt * 16 + lrow;
        float br  = b_ih[j]       + b_hh[j];
        float bz  = b_ih[128 + j] + b_hh[128 + j];
        float bin = b_ih[256 + j];
        float bhn = b_hh[256 + j];
#pragma unroll
        for (int mt = 0; mt < 2; ++mt) {
#pragma unroll
            for (int r = 0; r < 4; ++r) {
                int mloc = mt * 16 + lkg * 4 + r;
                int node = n0 + mloc;
                float rg  = acc[0][jt][mt][r] + br;
                float zg  = acc[1][jt][mt][r] + bz;
                float ing = acc[2][jt][mt][r] + bin;
                float hng = acc[3][jt][mt][r] + bhn;
                float rr = fsigmoid(rg);
                float zz = fsigmoid(zg);
                float nn = ftanh(ing + rr * hng);
                float mv = memory[(size_t)node * 128 + j];
                float h  = (1.0f - zz) * nn + zz * mv;
                out[(size_t)node * 128 + j] = (cntS[mloc] > 0.0f) ? h : mv;
            }
        }
    }
    if (tid < GNTF) {
        int node = n0 + tid;
        out[(size_t)N_NODES * 128 + node] = (cntS[tid] > 0.0f) ? ts0 : last_update[node];
    }
}

// ---------------------------------------------------------------------------
extern "C" void kernel_launch(void* const* d_in, const int* in_sizes, int n_in,
                              void* d_out, int out_size, void* d_ws, size_t ws_size,
                              hipStream_t stream) {
    const float* memory        = (const float*)d_in[0];
    const float* last_update   = (const float*)d_in[1];
    const float* timestamps    = (const float*)d_in[2];
    const float* edge_features = (const float*)d_in[3];
    const float* msg_W         = (const float*)d_in[4];
    const float* msg_b         = (const float*)d_in[5];
    const float* gru_W_ih      = (const float*)d_in[6];
    const float* gru_W_hh      = (const float*)d_in[7];
    const float* gru_b_ih      = (const float*)d_in[8];
    const float* gru_b_hh      = (const float*)d_in[9];
    const float* time_w        = (const float*)d_in[10];
    const float* time_b        = (const float*)d_in[11];
    const int*   src           = (const int*)d_in[12];
    const int*   dst           = (const int*)d_in[13];

    float* out = (float*)d_out;
    char* ws = (char*)d_ws;

    const size_t OFF_WGRU = 0;                                   // 256 KB
    const size_t OFF_WMSG = 262144;                              // 128 KB
    const size_t OFF_MSG  = 393216;                              // E*128 bf16
    const size_t SZ_MSG   = (size_t)E_EDGES * 128 * 2;           // 25.6 MB
    const size_t OFF_IDX  = OFF_MSG + SZ_MSG;                    // N*CAP u32
    const size_t SZ_IDX   = (size_t)N_NODES * CAP * 4;           // 9.6 MB
    const size_t OFF_CNT  = OFF_IDX + SZ_IDX;                    // N u32
    const size_t OFF_OVF  = OFF_CNT + (size_t)N_NODES * 4;
    const size_t WS_NEED  = OFF_OVF + 4 + (size_t)OVF_MAX * 8;

    short* wfrag_gru = (short*)(ws + OFF_WGRU);
    short* wfrag_msg = (short*)(ws + OFF_WMSG);
    const int TICKET_BLOCKS = (E_EDGES + 255) / 256;             // 391

    if (ws_size >= WS_NEED) {
        short* msgb = (short*)(ws + OFF_MSG);
        uint*  idxv = (uint*)(ws + OFF_IDX);
        uint*  cnt  = (uint*)(ws + OFF_CNT);
        uint*  ovf  = (uint*)(ws + OFF_OVF);

        hipMemsetAsync(ws + OFF_CNT, 0, (size_t)N_NODES * 4 + 16, stream);

        tgn_setup<<<768 + TICKET_BLOCKS, 256, 0, stream>>>(
            gru_W_ih, gru_W_hh, wfrag_gru, msg_W, wfrag_msg,
            src, dst, idxv, cnt, ovf);

        tgn_msg_bf<<<E_EDGES / MTE, 128, 0, stream>>>(
            memory, last_update, timestamps, edge_features, msg_b,
            time_w, time_b, src, dst, wfrag_msg, msgb);

        tgn_gru_bf64<<<N_NODES / GNT, 512, 0, stream>>>(
            memory, last_update, timestamps, gru_b_ih, gru_b_hh, wfrag_gru,
            msgb, idxv, cnt, ovf, out);
    } else {
        hipMemsetAsync(d_out, 0, (size_t)out_size * sizeof(float), stream);
        float* sums   = out;
        float* counts = out + (size_t)N_NODES * 128;

        tgn_setup<<<768, 256, 0, stream>>>(
            gru_W_ih, gru_W_hh, wfrag_gru, msg_W, wfrag_msg,
            src, dst, nullptr, nullptr, nullptr);

        tgn_msg_mfma<<<E_EDGES / TE, 256, 0, stream>>>(
            memory, last_update, timestamps, edge_features, msg_b,
            time_w, time_b, src, dst, wfrag_msg, sums, counts);

        tgn_gru_mfma<<<N_NODES / GNTF, 256, 0, stream>>>(
            memory, last_update, timestamps, gru_b_ih, gru_b_hh, wfrag_gru, out);
    }
}